// Round 2
// baseline (223.450 us; speedup 1.0000x reference)
//
#include <hip/hip_runtime.h>
#include <stdint.h>

#define F 128
#define KNB 16
#define TWO_F 256
#define ROWS 64          // rows per block
#define THREADS 256
#define XSTRIDE 264      // bf16 elems per x row (256 + 8 pad)
#define HSTR 133         // f32 stride of LN scratch rows (odd-ish -> spread banks)
#define LN_EPS 1e-5f
#define NEG_SLOPE 0.2f

typedef unsigned short u16;
typedef __bf16 bf16x8 __attribute__((ext_vector_type(8)));
typedef float f32x4 __attribute__((ext_vector_type(4)));

union BF8 { bf16x8 v; u16 us[8]; uint4 u4; };

__device__ __forceinline__ float b2f(u16 u) {
    union { float f; uint32_t i; } v; v.i = ((uint32_t)u) << 16; return v.f;
}
__device__ __forceinline__ u16 f2b(float f) {
    union { float f; uint32_t i; } v; v.f = f;
    uint32_t r = (v.i + 0x7FFFu + ((v.i >> 16) & 1u)) >> 16;
    return (u16)r;
}

// grid-stride-free cast: 8 f32 -> 8 bf16 per thread
extern "C" __global__ void cast_f32_bf16(const float* __restrict__ src,
                                         u16* __restrict__ dst, int n8) {
    const int i = blockIdx.x * blockDim.x + threadIdx.x;
    if (i >= n8) return;
    const float4* s = (const float4*)src + (size_t)i * 2;
    const float4 a = s[0], b = s[1];
    BF8 o;
    o.us[0] = f2b(a.x); o.us[1] = f2b(a.y); o.us[2] = f2b(a.z); o.us[3] = f2b(a.w);
    o.us[4] = f2b(b.x); o.us[5] = f2b(b.y); o.us[6] = f2b(b.z); o.us[7] = f2b(b.w);
    ((uint4*)dst)[i] = o.u4;
}

// MODE 0: all fp32 from global (no ws).  MODE 1: W from bf16 ws.  MODE 2: W + feat from bf16 ws.
template <int MODE>
__global__ __launch_bounds__(THREADS, 4)
void gnn_fused(const float* __restrict__ feat_f32, const u16* __restrict__ feat_bf,
               const int* __restrict__ adj,
               const float* __restrict__ W_f32, const u16* __restrict__ W_bf,
               const float* __restrict__ bias, const float* __restrict__ gamma,
               const float* __restrict__ beta,
               float* __restrict__ out, int N)
{
    __shared__ __align__(16) char smem[ROWS * XSTRIDE * 2 + ROWS * KNB * 4]; // 37888 B
    u16* xs   = (u16*)smem;                              // [64][264] bf16 x-tile
    int* adjs = (int*)(smem + ROWS * XSTRIDE * 2);       // [64][16]
    float* hb = (float*)smem;                            // epilogue overlay [64][HSTR] f32 (34048 B)

    const int tid = threadIdx.x;
    const long block0 = (long)blockIdx.x * ROWS;

    // ---- stage adjacency tile (1024 ints, 4 per thread) ----
    {
        const int flat = tid * 4;
        const long base = block0 * KNB + flat;
        const long total = (long)N * KNB;
        if (base + 3 < total) {
            *(int4*)(adjs + flat) = *(const int4*)(adj + base);
        } else {
            for (int j = 0; j < 4; ++j)
                adjs[flat + j] = (base + j < total) ? (int)adj[base + j] : -1;
        }
    }
    __syncthreads();

    // ---- prologue: x = [own_feats | masked neighbor mean] as bf16 in LDS ----
    {
        const int r  = tid >> 2;          // row in tile 0..63
        const int q4 = tid & 3;           // 32-feature slice
        const long rg = block0 + r;
        const int fbase = q4 * 32;
        u16* xrow = xs + r * XSTRIDE;

        if (rg < N) {
            // own features
            if (MODE == 2) {
                const uint4* src = (const uint4*)(feat_bf + rg * F + fbase);
                uint4* dst = (uint4*)(xrow + fbase);
                #pragma unroll
                for (int j = 0; j < 4; ++j) dst[j] = src[j];
            } else {
                const float4* s = (const float4*)(feat_f32 + rg * F + fbase);
                uint4* dst = (uint4*)(xrow + fbase);
                #pragma unroll
                for (int j = 0; j < 4; ++j) {
                    const float4 a = s[j * 2], b = s[j * 2 + 1];
                    BF8 o;
                    o.us[0] = f2b(a.x); o.us[1] = f2b(a.y); o.us[2] = f2b(a.z); o.us[3] = f2b(a.w);
                    o.us[4] = f2b(b.x); o.us[5] = f2b(b.y); o.us[6] = f2b(b.z); o.us[7] = f2b(b.w);
                    dst[j] = o.u4;
                }
            }

            // neighbor gather-mean (fp32 accumulate)
            float acc[32];
            #pragma unroll
            for (int t = 0; t < 32; ++t) acc[t] = 0.f;
            int cnt = 0;
            for (int k = 0; k < KNB; ++k) {
                const int idx = adjs[r * KNB + k];
                if (idx >= 0 && idx < N) {
                    ++cnt;
                    if (MODE == 2) {
                        const uint4* ns = (const uint4*)(feat_bf + (long)idx * F + fbase);
                        #pragma unroll
                        for (int j = 0; j < 4; ++j) {
                            BF8 u; u.u4 = ns[j];
                            #pragma unroll
                            for (int t = 0; t < 8; ++t) acc[j * 8 + t] += b2f(u.us[t]);
                        }
                    } else {
                        const float4* ns = (const float4*)(feat_f32 + (long)idx * F + fbase);
                        #pragma unroll
                        for (int j = 0; j < 8; ++j) {
                            const float4 a = ns[j];
                            acc[j * 4 + 0] += a.x; acc[j * 4 + 1] += a.y;
                            acc[j * 4 + 2] += a.z; acc[j * 4 + 3] += a.w;
                        }
                    }
                }
            }
            const float scale = 1.f / (float)(cnt > 0 ? cnt : 1);
            uint4* mdst = (uint4*)(xrow + F + fbase);
            #pragma unroll
            for (int j = 0; j < 4; ++j) {
                BF8 o;
                #pragma unroll
                for (int t = 0; t < 8; ++t) o.us[t] = f2b(acc[j * 8 + t] * scale);
                mdst[j] = o.u4;
            }
        } else {
            const uint4 z = make_uint4(0, 0, 0, 0);
            uint4* d0 = (uint4*)(xrow + fbase);
            uint4* d1 = (uint4*)(xrow + F + fbase);
            #pragma unroll
            for (int j = 0; j < 4; ++j) { d0[j] = z; d1[j] = z; }
        }
    }
    __syncthreads();

    // ---- GEMM: each wave computes h[16 rows x 128 cols] via mfma 16x16x32 bf16 ----
    const int wave = tid >> 6;
    const int lane = tid & 63;
    const int ln15 = lane & 15;
    const int quad = lane >> 4;
    const int rb   = wave * 16;

    f32x4 accf[8];
    #pragma unroll
    for (int c = 0; c < 8; ++c) accf[c] = (f32x4){0.f, 0.f, 0.f, 0.f};

    const u16* arow = xs + (rb + ln15) * XSTRIDE + quad * 8;

    #pragma unroll
    for (int ks = 0; ks < 8; ++ks) {
        const bf16x8 afrag = *(const bf16x8*)(arow + ks * 32);
        #pragma unroll
        for (int c = 0; c < 8; ++c) {
            bf16x8 bfrag;
            if (MODE >= 1) {
                bfrag = *(const bf16x8*)(W_bf + (size_t)(c * 16 + ln15) * TWO_F + quad * 8 + ks * 32);
            } else {
                const float* wr = W_f32 + (size_t)(c * 16 + ln15) * TWO_F + quad * 8 + ks * 32;
                const float4 a = *(const float4*)wr, b = *(const float4*)(wr + 4);
                BF8 o;
                o.us[0] = f2b(a.x); o.us[1] = f2b(a.y); o.us[2] = f2b(a.z); o.us[3] = f2b(a.w);
                o.us[4] = f2b(b.x); o.us[5] = f2b(b.y); o.us[6] = f2b(b.z); o.us[7] = f2b(b.w);
                bfrag = o.v;
            }
            accf[c] = __builtin_amdgcn_mfma_f32_16x16x32_bf16(afrag, bfrag, accf[c], 0, 0, 0);
        }
    }

    // bias per (col-tile, lane-col)
    float bval[8];
    #pragma unroll
    for (int c = 0; c < 8; ++c) bval[c] = bias[c * 16 + ln15];

    // xs no longer needed; overlay hb (crosses wave regions -> barrier first)
    __syncthreads();

    // ---- write h to LDS scratch (C/D layout: col = lane&15, row = quad*4 + reg) ----
    #pragma unroll
    for (int c = 0; c < 8; ++c) {
        #pragma unroll
        for (int t = 0; t < 4; ++t) {
            const int rr = quad * 4 + t;
            hb[(rb + rr) * HSTR + c * 16 + ln15] = accf[c][t] + bval[c];
        }
    }
    __syncthreads();

    // ---- LayerNorm + LeakyReLU: 4 lanes per row ----
    const int er = lane >> 2;                  // row 0..15 (within wave slice)
    const int eq = lane & 3;                   // 32-col slice
    const float* hr = hb + (rb + er) * HSTR + eq * 32;
    float sum = 0.f, sq = 0.f;
    #pragma unroll
    for (int t = 0; t < 32; ++t) { const float v = hr[t]; sum += v; sq += v * v; }
    sum += __shfl_xor(sum, 1); sq += __shfl_xor(sq, 1);
    sum += __shfl_xor(sum, 2); sq += __shfl_xor(sq, 2);

    const float mu   = sum * (1.f / 128.f);
    const float var  = sq * (1.f / 128.f) - mu * mu;
    const float rsig = rsqrtf(fmaxf(var, 0.f) + LN_EPS);

    const long org = block0 + rb + er;
    if (org < N) {
        const int cb = eq * 32;
        float* orow = out + org * F + cb;
        #pragma unroll
        for (int j = 0; j < 8; ++j) {
            const float4 g  = *(const float4*)(gamma + cb + j * 4);
            const float4 bt = *(const float4*)(beta  + cb + j * 4);
            float4 o;
            o.x = (hr[j * 4 + 0] - mu) * rsig * g.x + bt.x;
            o.y = (hr[j * 4 + 1] - mu) * rsig * g.y + bt.y;
            o.z = (hr[j * 4 + 2] - mu) * rsig * g.z + bt.z;
            o.w = (hr[j * 4 + 3] - mu) * rsig * g.w + bt.w;
            o.x = (o.x >= 0.f) ? o.x : NEG_SLOPE * o.x;
            o.y = (o.y >= 0.f) ? o.y : NEG_SLOPE * o.y;
            o.z = (o.z >= 0.f) ? o.z : NEG_SLOPE * o.z;
            o.w = (o.w >= 0.f) ? o.w : NEG_SLOPE * o.w;
            *(float4*)(orow + j * 4) = o;
        }
    }
}

extern "C" void kernel_launch(void* const* d_in, const int* in_sizes, int n_in,
                              void* d_out, int out_size, void* d_ws, size_t ws_size,
                              hipStream_t stream) {
    const float* feat  = (const float*)d_in[0];
    const int*   adj   = (const int*)d_in[1];
    const float* W     = (const float*)d_in[2];
    const float* bias  = (const float*)d_in[3];
    const float* gamma = (const float*)d_in[4];
    const float* beta  = (const float*)d_in[5];
    float* out = (float*)d_out;

    const int N = in_sizes[0] / F;
    const size_t needW = (size_t)TWO_F * F * sizeof(u16);        // 65536 B
    const size_t needF = (size_t)N * F * sizeof(u16);            // ~25.6 MB
    u16* wsW = (u16*)d_ws;
    u16* wsF = (u16*)((char*)d_ws + needW);

    const int mode = (ws_size >= needW + needF) ? 2 : (ws_size >= needW ? 1 : 0);

    if (mode >= 1) {
        const int n8 = TWO_F * F / 8;
        cast_f32_bf16<<<dim3((n8 + 255) / 256), dim3(256), 0, stream>>>(W, wsW, n8);
    }
    if (mode == 2) {
        const int n8 = N * F / 8;   // N*F divisible by 8
        cast_f32_bf16<<<dim3((n8 + 255) / 256), dim3(256), 0, stream>>>(feat, wsF, n8);
    }

    const int blocks = (N + ROWS - 1) / ROWS;
    if (mode == 2) {
        gnn_fused<2><<<dim3(blocks), dim3(THREADS), 0, stream>>>(feat, wsF, adj, W, wsW, bias, gamma, beta, out, N);
    } else if (mode == 1) {
        gnn_fused<1><<<dim3(blocks), dim3(THREADS), 0, stream>>>(feat, wsF, adj, W, wsW, bias, gamma, beta, out, N);
    } else {
        gnn_fused<0><<<dim3(blocks), dim3(THREADS), 0, stream>>>(feat, wsF, adj, W, wsW, bias, gamma, beta, out, N);
    }
}